// Round 1
// baseline (237.312 us; speedup 1.0000x reference)
//
#include <hip/hip_runtime.h>
#include <math.h>

// FairnessLoss: fused CE + group-mean-variance fairness penalty.
// N=262144 rows, C=1000 classes, G=8 groups, lambda=0.1, eps=1e-8.
//
// Layout of d_ws (float view):
//   ws[0]      : total per-sample-loss sum
//   ws[1..8]   : per-group loss sums
//   (uint)ws[9..16] : per-group counts

#define N_ROWS   262144
#define C_COLS   1000
#define G_GROUPS 8
#define NF4      250   // 1000 floats = 250 float4 per row

__global__ __launch_bounds__(256)
void fair_ce_kernel(const float* __restrict__ logits,
                    const int*   __restrict__ targets,
                    const int*   __restrict__ gids,
                    float*       __restrict__ ws) {
    __shared__ float        s_total;
    __shared__ float        s_gsum[G_GROUPS];
    __shared__ unsigned int s_gcnt[G_GROUPS];

    const int tid = threadIdx.x;
    if (tid == 0) s_total = 0.f;
    if (tid < G_GROUPS) { s_gsum[tid] = 0.f; s_gcnt[tid] = 0u; }
    __syncthreads();

    const int lane  = tid & 63;
    const int wave  = tid >> 6;                 // 0..3 (4 waves / block)
    const int gwave = blockIdx.x * 4 + wave;
    const int nwave = gridDim.x * 4;

    for (int row = gwave; row < N_ROWS; row += nwave) {
        const float4* rowp = (const float4*)(logits + (size_t)row * C_COLS);

        // Load whole row into registers: lane holds float4s at f = lane + 64*j.
        float4 v[4];
#pragma unroll
        for (int j = 0; j < 4; ++j) {
            const int f = lane + 64 * j;
            if (f < NF4) v[j] = rowp[f];
            else         v[j] = make_float4(-INFINITY, -INFINITY, -INFINITY, -INFINITY);
        }

        // Row max.
        float m = -INFINITY;
#pragma unroll
        for (int j = 0; j < 4; ++j)
            m = fmaxf(m, fmaxf(fmaxf(v[j].x, v[j].y), fmaxf(v[j].z, v[j].w)));
#pragma unroll
        for (int off = 32; off; off >>= 1)
            m = fmaxf(m, __shfl_xor(m, off));

        // Sum of exp(x - m). Invalid slots are -inf -> exp = 0.
        float s = 0.f;
#pragma unroll
        for (int j = 0; j < 4; ++j) {
            s += __expf(v[j].x - m) + __expf(v[j].y - m)
               + __expf(v[j].z - m) + __expf(v[j].w - m);
        }
#pragma unroll
        for (int off = 32; off; off >>= 1)
            s += __shfl_xor(s, off);

        if (lane == 0) {
            const int   t  = targets[row];
            const float tv = logits[(size_t)row * C_COLS + t];   // L2 hit
            const float ps = m + __logf(s) - tv;                 // -log_softmax[target]
            const int   g  = gids[row];
            atomicAdd(&s_total, ps);
            atomicAdd(&s_gsum[g], ps);
            atomicAdd(&s_gcnt[g], 1u);
        }
    }

    __syncthreads();
    if (tid == 0) atomicAdd(&ws[0], s_total);
    if (tid < G_GROUPS) {
        atomicAdd(&ws[1 + tid], s_gsum[tid]);
        atomicAdd(&((unsigned int*)ws)[9 + tid], s_gcnt[tid]);
    }
}

__global__ void fair_finalize(const float* __restrict__ ws,
                              float* __restrict__ out) {
    if (threadIdx.x != 0 || blockIdx.x != 0) return;
    const float base = ws[0] / (float)N_ROWS;
    const unsigned int* cnt = ((const unsigned int*)ws) + 9;
    float means[G_GROUPS];
    float mb = 0.f;
#pragma unroll
    for (int g = 0; g < G_GROUPS; ++g) {
        means[g] = ws[1 + g] / fmaxf((float)cnt[g], 1.f);
        mb += means[g];
    }
    mb *= (1.f / G_GROUPS);
    float var = 0.f;
#pragma unroll
    for (int g = 0; g < G_GROUPS; ++g) {
        const float d = means[g] - mb;
        var += d * d;
    }
    var *= (1.f / G_GROUPS);
    out[0] = base + 0.1f * sqrtf(var + 1e-8f);
}

extern "C" void kernel_launch(void* const* d_in, const int* in_sizes, int n_in,
                              void* d_out, int out_size, void* d_ws, size_t ws_size,
                              hipStream_t stream) {
    const float* logits  = (const float*)d_in[0];
    const int*   targets = (const int*)d_in[1];
    const int*   gids    = (const int*)d_in[2];
    float*       out     = (float*)d_out;
    float*       ws      = (float*)d_ws;

    // Zero the 17-word accumulator region (capturable as a memset node).
    hipMemsetAsync(ws, 0, 17 * sizeof(float), stream);

    const int blocks = 2048;   // 8192 waves -> 32 rows per wave
    fair_ce_kernel<<<blocks, 256, 0, stream>>>(logits, targets, gids, ws);
    fair_finalize<<<1, 64, 0, stream>>>(ws, out);
}